// Round 4
// baseline (733.508 us; speedup 1.0000x reference)
//
#include <hip/hip_runtime.h>
#include <stdint.h>

// SNN: conv(2->8,3x3,SAME on 512x32) -> LIF(T=4) -> FC 131072->512 -> LIF
//      -> FC 512->512 -> LIF -> mean over T -> FC 512->16
// All fp32 I/O. tau=2: v = 0.5*v + x; spike v>=1; hard reset to 0.
//
// Output layout (concat, fp32):
//   out:        (128,16)            @ 0
//   conv_spk:   (128,4,8,512,32)    @ 2048
//   input_spk:  (128,4,512)         @ 67110912
//   hidden_spk: (128,4,512)         @ 67373056

#define OFF_CONV  2048ll
#define OFF_IN    67110912ll
#define OFF_HID   67373056ll

typedef short bf16x8 __attribute__((ext_vector_type(8)));
typedef float f32x4  __attribute__((ext_vector_type(4)));

__device__ __forceinline__ unsigned short f2bf(float f) {
  unsigned u = __float_as_uint(f);
  u += 0x7FFFu + ((u >> 16) & 1u);   // round-to-nearest-even to bf16
  return (unsigned short)(u >> 16);
}

// expand 4 spike bits (bit0 of each byte of x) -> two dwords of packed bf16 {0,1}
__device__ __forceinline__ void expand2(unsigned x, unsigned& o0, unsigned& o1) {
  o0 = (x & 1u) * 0x3F80u | (x & 0x100u) * 0x3F8000u;
  unsigned y = x >> 16;
  o1 = (y & 1u) * 0x3F80u | (y & 0x100u) * 0x3F8000u;
}

// ---------------------------------------------------------------------------
// Kernel 1: conv + LIF over T=4. One thread per (b, co, h, w0..w0+3).
// Writes fp32 spikes to d_out (nontemporal: never re-read) and 4-bit pattern
// bytes to ws (re-read by gemm).
// ---------------------------------------------------------------------------
__global__ __launch_bounds__(256) void conv_lif_kernel(
    const float* __restrict__ x, const float* __restrict__ wc,
    float* __restrict__ out, unsigned char* __restrict__ patt)
{
  __shared__ float wcs[144];
  int tid = threadIdx.x;
  if (tid < 144) wcs[tid] = wc[tid];
  __syncthreads();

  int idx = blockIdx.x * 256 + tid;        // b*32768 + co*4096 + h*8 + wq
  int b   = idx >> 15;
  int k4  = idx & 32767;
  int co  = k4 >> 12;
  int rem = k4 & 4095;
  int h   = rem >> 3;
  int w0  = (rem & 7) * 4;

  const float* xb = x + (long long)b * 32768;  // (2, 512, 32) per batch
  float c[4] = {0.f, 0.f, 0.f, 0.f};
#pragma unroll
  for (int ci = 0; ci < 2; ++ci) {
    const float* xc = xb + ci * 16384;
    const float* wk = wcs + co * 18 + ci * 9;
    float win[3][6];
#pragma unroll
    for (int r = 0; r < 3; ++r) {
      int hh = h - 1 + r;
      if (hh >= 0 && hh < 512) {
        const float* row = xc + hh * 32;
        float4 m = *(const float4*)(row + w0);
        win[r][1] = m.x; win[r][2] = m.y; win[r][3] = m.z; win[r][4] = m.w;
        win[r][0] = (w0 > 0)  ? row[w0 - 1] : 0.f;
        win[r][5] = (w0 < 28) ? row[w0 + 4] : 0.f;
      } else {
#pragma unroll
        for (int j = 0; j < 6; ++j) win[r][j] = 0.f;
      }
    }
#pragma unroll
    for (int r = 0; r < 3; ++r)
#pragma unroll
      for (int dw = 0; dw < 3; ++dw) {
        float wgt = wk[r * 3 + dw];
#pragma unroll
        for (int j = 0; j < 4; ++j) c[j] += win[r][j + dw] * wgt;
      }
  }

  // LIF, exactly mirroring reference fp32 semantics
  int k = co * 16384 + h * 32 + w0;
  float* ob = out + OFF_CONV + (long long)b * 524288 + k;
  float v[4] = {0.f, 0.f, 0.f, 0.f};
  unsigned p[4] = {0, 0, 0, 0};
#pragma unroll
  for (int t = 0; t < 4; ++t) {
    f32x4 sv;
#pragma unroll
    for (int j = 0; j < 4; ++j) {
      v[j] = v[j] * 0.5f + c[j];
      int si = (v[j] >= 1.0f) ? 1 : 0;
      sv[j] = (float)si;
      if (si) v[j] = 0.f;
      p[j] |= (unsigned)si << t;
    }
    __builtin_nontemporal_store(sv, (f32x4*)(ob + t * 131072));
  }
  unsigned pb = p[0] | (p[1] << 8) | (p[2] << 16) | (p[3] << 24);
  *(unsigned*)(patt + (long long)b * 131072 + k) = pb;
}

// ---------------------------------------------------------------------------
// Kernel 2: big GEMM  Z1[m=t*128+b][n] = sum_k spike[t][b][k] * w1[n][k]
// A-fragments come straight from pattern bytes (uint2 per lane, in-register
// bit-expand for the wave's own t) -- no A LDS at all. B (w1) split hi/lo
// bf16 into double-buffered LDS; single barrier per K-step; next step's B
// floats + patt bytes prefetched into registers under the MFMA phase.
// ---------------------------------------------------------------------------
__global__ __launch_bounds__(512, 2) void gemm_kernel(
    const unsigned char* __restrict__ patt, const float* __restrict__ w1,
    float* __restrict__ partials, int steps)
{
  __shared__ unsigned short Bh[2][128][36];  // 36 shorts = 18 dw: gcd(18,32)=2
  __shared__ unsigned short Bl[2][128][36];  // -> 16 rows hit distinct banks

  const int tid   = threadIdx.x;
  const int nt    = blockIdx.x & 3;          // N-tile (128 w1 rows)
  const int chunk = blockIdx.x >> 2;         // split-K chunk
  const long long k0 = (long long)chunk * steps * 32;

  const int r  = tid >> 2;                   // B staging row 0..127
  const int ko = (tid & 3) * 8;              // B staging k-offset (8 floats)
  const float* pB = w1 + (long long)(nt * 128 + r) * 131072 + k0 + ko;

  const int lane = tid & 63;
  const int wid  = tid >> 6;                 // 0..7
  const int t    = wid >> 1;                 // timestep of this wave
  const int nh   = wid & 1;                  // n-half (64)
  const int l15 = lane & 15, quad = lane >> 4;

  // per-lane patt base: row = fm*16 + l15, bytes quad*8..+7 of each K-step
  const unsigned char* pA = patt + (long long)l15 * 131072 + k0 + quad * 8;

  f32x4 acc[8][4];
#pragma unroll
  for (int i = 0; i < 8; ++i)
#pragma unroll
    for (int j = 0; j < 4; ++j) acc[i][j] = (f32x4){0.f, 0.f, 0.f, 0.f};

  // prologue: prefetch step 0
  float4 fB0 = *(const float4*)(pB);
  float4 fB1 = *(const float4*)(pB + 4);
  uint2 pa[8];
#pragma unroll
  for (int f = 0; f < 8; ++f)
    pa[f] = *(const uint2*)(pA + (long long)f * 2097152);  // f*16 rows

  for (int s = 0; s < steps; ++s) {
    const int buf = s & 1;

    // --- B: fp32 -> (hi, lo) bf16 pair (identical arithmetic to r2) ---
    {
      float fv[8] = {fB0.x, fB0.y, fB0.z, fB0.w, fB1.x, fB1.y, fB1.z, fB1.w};
      unsigned hp[4], lp[4];
#pragma unroll
      for (int i = 0; i < 4; ++i) {
        unsigned short h0 = f2bf(fv[2 * i]);
        unsigned short h1 = f2bf(fv[2 * i + 1]);
        float r0 = fv[2 * i]     - __uint_as_float((unsigned)h0 << 16);
        float r1 = fv[2 * i + 1] - __uint_as_float((unsigned)h1 << 16);
        hp[i] = (unsigned)h0 | ((unsigned)h1 << 16);
        lp[i] = (unsigned)f2bf(r0) | ((unsigned)f2bf(r1) << 16);
      }
      *(uint4*)&Bh[buf][r][ko] = make_uint4(hp[0], hp[1], hp[2], hp[3]);
      *(uint4*)&Bl[buf][r][ko] = make_uint4(lp[0], lp[1], lp[2], lp[3]);
    }

    // --- prefetch step s+1 (latency hidden under barrier + MFMA) ---
    const long long sn = (s + 1 < steps) ? (s + 1) : s;
    float4 nB0 = *(const float4*)(pB + sn * 32);
    float4 nB1 = *(const float4*)(pB + sn * 32 + 4);
    uint2 npa[8];
#pragma unroll
    for (int f = 0; f < 8; ++f)
      npa[f] = *(const uint2*)(pA + (long long)f * 2097152 + sn * 32);

    __syncthreads();   // one barrier per step (double-buffered B)

    bf16x8 bh[4], bl[4];
#pragma unroll
    for (int f = 0; f < 4; ++f) {
      bh[f] = *(const bf16x8*)&Bh[buf][nh * 64 + f * 16 + l15][quad * 8];
      bl[f] = *(const bf16x8*)&Bl[buf][nh * 64 + f * 16 + l15][quad * 8];
    }

#pragma unroll
    for (int fm = 0; fm < 8; ++fm) {
      // expand bit t of this fragment's 8 pattern bytes -> 8 bf16 {0,1}
      unsigned x0 = (pa[fm].x >> t) & 0x01010101u;
      unsigned x1 = (pa[fm].y >> t) & 0x01010101u;
      unsigned o0, o1, o2, o3;
      expand2(x0, o0, o1);
      expand2(x1, o2, o3);
      union { uint4 u; bf16x8 v; } au;
      au.u = make_uint4(o0, o1, o2, o3);
#pragma unroll
      for (int fn = 0; fn < 4; ++fn) {
        acc[fm][fn] = __builtin_amdgcn_mfma_f32_16x16x32_bf16(au.v, bh[fn], acc[fm][fn], 0, 0, 0);
        acc[fm][fn] = __builtin_amdgcn_mfma_f32_16x16x32_bf16(au.v, bl[fn], acc[fm][fn], 0, 0, 0);
      }
    }

    fB0 = nB0; fB1 = nB1;
#pragma unroll
    for (int f = 0; f < 8; ++f) pa[f] = npa[f];
  }

  // epilogue: partials[chunk][t*128+b][n]; D: row = quad*4+reg (b), col = l15
  float* pc = partials + (long long)chunk * 262144;
#pragma unroll
  for (int fm = 0; fm < 8; ++fm)
#pragma unroll
    for (int fn = 0; fn < 4; ++fn) {
      int m = t * 128 + fm * 16 + quad * 4;
      int n = nt * 128 + nh * 64 + fn * 16 + l15;
#pragma unroll
      for (int rg = 0; rg < 4; ++rg)
        pc[(long long)(m + rg) * 512 + n] = acc[fm][fn][rg];
    }
}

// ---------------------------------------------------------------------------
// Kernel 3: split-K reduce (deterministic ascending-chunk order)
// ---------------------------------------------------------------------------
__global__ __launch_bounds__(256) void reduce_kernel(
    const float* __restrict__ partials, float* __restrict__ z1, int S)
{
  int idx = blockIdx.x * 256 + threadIdx.x;  // 0..262143
  float a = 0.f;
  for (int c = 0; c < S; ++c) a += partials[(long long)c * 262144 + idx];
  z1[idx] = a;
}

// ---------------------------------------------------------------------------
// Kernel 4: per-batch FC pipeline: LIF1 -> FC2 -> LIF2 -> mean -> readout.
// One block per b (512 threads = one neuron each). w2 rows read directly
// with float4 (ascending-k order preserved -> bitwise-identical z2).
// ---------------------------------------------------------------------------
__global__ __launch_bounds__(512) void fc_kernel(
    const float* __restrict__ z1, const float* __restrict__ w2,
    const float* __restrict__ wout, float* __restrict__ out)
{
  int b = blockIdx.x;
  int n = threadIdx.x;
  __shared__ float s1s[512];
  __shared__ float red[512];

  const float* wrow = w2 + (long long)n * 512;
  float v1 = 0.f, v2 = 0.f, ssum = 0.f;
#pragma unroll
  for (int t = 0; t < 4; ++t) {
    float z = z1[((t * 128 + b) << 9) + n];
    v1 = v1 * 0.5f + z;
    float s1 = (v1 >= 1.0f) ? 1.f : 0.f;
    out[OFF_IN + ((long long)b * 4 + t) * 512 + n] = s1;
    if (s1 != 0.f) v1 = 0.f;
    s1s[n] = s1;
    __syncthreads();

    float z2 = 0.f;
#pragma unroll 8
    for (int k = 0; k < 512; k += 4) {
      float4 w = *(const float4*)(wrow + k);
      z2 += s1s[k]     * w.x;
      z2 += s1s[k + 1] * w.y;
      z2 += s1s[k + 2] * w.z;
      z2 += s1s[k + 3] * w.w;
    }
    v2 = v2 * 0.5f + z2;
    float s2 = (v2 >= 1.0f) ? 1.f : 0.f;
    out[OFF_HID + ((long long)b * 4 + t) * 512 + n] = s2;
    if (s2 != 0.f) v2 = 0.f;
    ssum += s2;
    __syncthreads();                     // before s1s overwrite next t
  }

  s1s[n] = ssum * 0.25f;                 // mean spikes, reuse LDS
  __syncthreads();

  int o = n & 15, part = n >> 4;         // 16 outputs x 32 partials
  float p = 0.f;
#pragma unroll
  for (int j = 0; j < 16; ++j)
    p += s1s[part * 16 + j] * wout[o * 512 + part * 16 + j];
  red[n] = p;
  __syncthreads();
  if (n < 16) {
    float a = 0.f;
#pragma unroll
    for (int pp = 0; pp < 32; ++pp) a += red[pp * 16 + n];
    out[b * 16 + n] = a;
  }
}

// ---------------------------------------------------------------------------
extern "C" void kernel_launch(void* const* d_in, const int* in_sizes, int n_in,
                              void* d_out, int out_size, void* d_ws, size_t ws_size,
                              hipStream_t stream) {
  const float* x     = (const float*)d_in[0];
  const float* wconv = (const float*)d_in[1];
  const float* w1    = (const float*)d_in[2];
  const float* w2    = (const float*)d_in[3];
  const float* wout  = (const float*)d_in[4];
  float* out = (float*)d_out;
  char* ws = (char*)d_ws;

  unsigned char* patt = (unsigned char*)ws;               // 16 MB
  float* z1       = (float*)(ws + 16777216);              // 1 MB
  float* partials = (float*)(ws + 16777216 + 1048576);    // S MB

  int S = 64;
  while (S > 1 && (size_t)(17825792ull + (size_t)S * 1048576ull) > ws_size) S >>= 1;
  int steps = 4096 / S;  // K-steps of 32 per chunk

  hipLaunchKernelGGL(conv_lif_kernel, dim3(16384), dim3(256), 0, stream,
                     x, wconv, out, patt);
  hipLaunchKernelGGL(gemm_kernel, dim3(4 * S), dim3(512), 0, stream,
                     patt, w1, partials, steps);
  hipLaunchKernelGGL(reduce_kernel, dim3(1024), dim3(256), 0, stream,
                     partials, z1, S);
  hipLaunchKernelGGL(fc_kernel, dim3(128), dim3(512), 0, stream,
                     z1, w2, wout, out);
}